// Round 5
// baseline (70.417 us; speedup 1.0000x reference)
//
#include <hip/hip_runtime.h>
#include <hip/hip_bf16.h>

// RotatedEmbedding: out[m,:] = W[ids[m],:] @ R  (M=16384, K=N=1024)
// prep: R -> RT bf16 (transposed). Main: FUSED gather-GEMM, 256x256 tile,
// BK=32, 8 waves, 3 LDS buffers. A = gathered W rows (f32), reg-staged 2
// tiles ahead (T14), converted+ds_written (swizzled) 1 tile ahead. B = RT
// via global_load_lds w/ pre-swizzled source (rule #21). Counted vmcnt (T4),
// setprio (T5), XCD-bijective swizzle (T1). Loop unrolled x2 for static
// A-reg-set indexing (rule #20).

typedef __attribute__((ext_vector_type(4))) float f32x4;
typedef __attribute__((ext_vector_type(8))) short s16x8;

#define DIM 1024
#define NT 32  // K-tiles (BK=32)

__device__ __forceinline__ short f2bf(float f) {
  unsigned u = __float_as_uint(f);
  unsigned r = (u + 0x7FFFu + ((u >> 16) & 1u)) >> 16;  // RNE
  return (short)r;
}

__device__ __forceinline__ void gload_lds16(const void* g, void* l) {
  __builtin_amdgcn_global_load_lds((const __attribute__((address_space(1))) void*)g,
                                   (__attribute__((address_space(3))) void*)l, 16, 0, 0);
}

// R [K][N] f32 -> RT [N][K] bf16
__global__ __launch_bounds__(256) void convert_R_kernel(const float* __restrict__ R,
                                                        short* __restrict__ RT) {
  __shared__ float tile[32][33];
  const int bx = blockIdx.x, by = blockIdx.y;
  const int tx = threadIdx.x, ty = threadIdx.y;
#pragma unroll
  for (int i = 0; i < 4; ++i)
    tile[ty + i * 8][tx] = R[(size_t)(by * 32 + ty + i * 8) * DIM + bx * 32 + tx];
  __syncthreads();
#pragma unroll
  for (int i = 0; i < 4; ++i)
    RT[(size_t)(bx * 32 + ty + i * 8) * DIM + by * 32 + tx] = f2bf(tile[tx][ty + i * 8]);
}

// Fused gather-GEMM. Grid 256 x 512 threads. Dynamic LDS 99328 B:
// [0,48K) A bufs x3, [48K,96K) B bufs x3 (16 KB each, rows of 64 B,
// 16B-chunk slot = logical_chunk ^ (row&3)), [96K,+1K) sIds.
__global__ __launch_bounds__(512, 2) void rot_embed_gemm(const float* __restrict__ W,
                                                         const short* __restrict__ RT,
                                                         const int* __restrict__ ids,
                                                         float* __restrict__ out) {
  extern __shared__ char smem[];

  const int t = threadIdx.x;
  const int b = blockIdx.x;
  // T1: XCD-bijective (256 blocks): XCD x -> m-panels [x*8,(x+1)*8), all n
  const int swz = (b & 7) * 32 + (b >> 3);
  const int m0 = (swz >> 2) * 256;
  const int n0 = (swz & 3) * 256;

  int* sIds = (int*)(smem + 98304);
  if (t < 256) sIds[t] = ids[m0 + t];
  __syncthreads();

  const int lane = t & 63;
  const int w = t >> 6;
  const int wm = w >> 2, wn = w & 3;
  const int fr = lane & 15, fq = lane >> 4;

  char* const ldsA = smem;
  char* const ldsB = smem + 49152;

  // B staging: 2 gload_lds/thread, linear LDS dest, pre-swizzled global source
  const int srow = w * 16 + (lane >> 2);
  const int schunk = ((lane & 3) ^ ((lane >> 2) & 3)) * 8;
  const short* gB0 = RT + (size_t)(n0 + srow) * DIM + schunk;
  const short* gB1 = RT + (size_t)(n0 + 128 + srow) * DIM + schunk;

  // A gather (reg-staged): thread t -> row rA=t>>1, f32 cols [h*16,(h+1)*16)
  const int rA = t >> 1;
  const int h = t & 1;
  const float* gA = W + (size_t)sIds[rA] * DIM + h * 16;
  const int wo0 = rA * 64 + (((h * 2) ^ (rA & 3)) << 4);      // logical chunk 2h
  const int wo1 = rA * 64 + (((h * 2 + 1) ^ (rA & 3)) << 4);  // chunk 2h+1

#define ALD(av, kt)                                  \
  {                                                  \
    const f32x4* p = (const f32x4*)(gA + (kt) * 32); \
    av[0] = p[0]; av[1] = p[1]; av[2] = p[2]; av[3] = p[3]; \
  }
#define BST(off, kt)                                                  \
  {                                                                   \
    gload_lds16(gB0 + (kt) * 32, ldsB + (off) + w * 1024);            \
    gload_lds16(gB1 + (kt) * 32, ldsB + (off) + w * 1024 + 8192);     \
  }
#define AWR(av, off)                                                  \
  {                                                                   \
    s16x8 p0, p1;                                                     \
    _Pragma("unroll") for (int e = 0; e < 4; ++e) {                   \
      p0[e] = f2bf(av[0][e]); p0[4 + e] = f2bf(av[1][e]);             \
      p1[e] = f2bf(av[2][e]); p1[4 + e] = f2bf(av[3][e]);             \
    }                                                                 \
    *(s16x8*)(ldsA + (off) + wo0) = p0;                               \
    *(s16x8*)(ldsA + (off) + wo1) = p1;                               \
  }
#define COMPUTE(off)                                                         \
  {                                                                          \
    const char* Abuf = ldsA + (off);                                         \
    const char* Bbuf = ldsB + (off);                                         \
    const int sc = (fq ^ (fr & 3)) << 4;                                     \
    s16x8 af[8], bfv[4];                                                     \
    _Pragma("unroll") for (int mi = 0; mi < 8; ++mi)                         \
        af[mi] = *(const s16x8*)(Abuf + (wm * 128 + mi * 16 + fr) * 64 + sc);\
    _Pragma("unroll") for (int nj = 0; nj < 4; ++nj)                         \
        bfv[nj] = *(const s16x8*)(Bbuf + (wn * 64 + nj * 16 + fr) * 64 + sc);\
    __builtin_amdgcn_s_setprio(1);                                           \
    _Pragma("unroll") for (int mi = 0; mi < 8; ++mi)                         \
        _Pragma("unroll") for (int nj = 0; nj < 4; ++nj)                     \
            acc[mi][nj] = __builtin_amdgcn_mfma_f32_16x16x32_bf16(           \
                af[mi], bfv[nj], acc[mi][nj], 0, 0, 0);                      \
    __builtin_amdgcn_s_setprio(0);                                           \
  }

  f32x4 acc[8][4];
#pragma unroll
  for (int i = 0; i < 8; ++i)
#pragma unroll
    for (int j = 0; j < 4; ++j) acc[i][j] = (f32x4)0.0f;

  f32x4 avE[4], avO[4];  // A-reg sets: even / odd tiles (static indexing)

  // ---- prologue: issue order A0, B0, A1, B1 (pinned) ----
  ALD(avE, 0);
  __builtin_amdgcn_sched_barrier(0);
  BST(0, 0);
  __builtin_amdgcn_sched_barrier(0);
  ALD(avO, 1);
  __builtin_amdgcn_sched_barrier(0);
  BST(16384, 1);
  __builtin_amdgcn_sched_barrier(0);
  asm volatile("s_waitcnt vmcnt(8)" ::: "memory");  // A0 landed
  AWR(avE, 0);
  __builtin_amdgcn_sched_barrier(0);
  asm volatile("s_waitcnt vmcnt(6) lgkmcnt(0)" ::: "memory");  // B0 landed + A0 writes
  __builtin_amdgcn_s_barrier();
  __builtin_amdgcn_sched_barrier(0);

  int offR = 0, offW = 16384, offS = 32768;

  for (int kt = 0; kt < NT; kt += 2) {
    // ---- even body: compute tile kt ----
    if (kt + 2 < NT) { BST(offS, kt + 2); ALD(avE, kt + 2); }  // 6 vmem
    __builtin_amdgcn_sched_barrier(0);
    if (kt + 2 < NT)
      asm volatile("s_waitcnt vmcnt(6)" ::: "memory");  // A(kt+1),B(kt+1) landed
    else
      asm volatile("s_waitcnt vmcnt(0)" ::: "memory");
    __builtin_amdgcn_sched_barrier(0);
    AWR(avO, offW);  // tile kt+1 -> buf W
    COMPUTE(offR);
    asm volatile("s_waitcnt lgkmcnt(0)" ::: "memory");  // A-writes visible pre-barrier
    __builtin_amdgcn_s_barrier();
    __builtin_amdgcn_sched_barrier(0);
    { const int tmp = offR; offR = offW; offW = offS; offS = tmp; }

    // ---- odd body: compute tile kt+1 ----
    if (kt + 3 < NT) { BST(offS, kt + 3); ALD(avO, kt + 3); }
    __builtin_amdgcn_sched_barrier(0);
    if (kt + 3 < NT)
      asm volatile("s_waitcnt vmcnt(6)" ::: "memory");
    else
      asm volatile("s_waitcnt vmcnt(0)" ::: "memory");
    __builtin_amdgcn_sched_barrier(0);
    if (kt + 2 < NT) AWR(avE, offW);  // tile kt+2 -> buf W
    COMPUTE(offR);
    asm volatile("s_waitcnt lgkmcnt(0)" ::: "memory");
    __builtin_amdgcn_s_barrier();
    __builtin_amdgcn_sched_barrier(0);
    { const int tmp = offR; offR = offW; offW = offS; offS = tmp; }
  }

  // ---- epilogue: D col=lane&15, row=(lane>>4)*4+reg (m89-verified) ----
#pragma unroll
  for (int mi = 0; mi < 8; ++mi)
#pragma unroll
    for (int nj = 0; nj < 4; ++nj) {
      float* op = out + (size_t)(m0 + wm * 128 + mi * 16 + fq * 4) * DIM +
                  (n0 + wn * 64 + nj * 16 + fr);
#pragma unroll
      for (int r = 0; r < 4; ++r) op[(size_t)r * DIM] = acc[mi][nj][r];
    }
#undef ALD
#undef BST
#undef AWR
#undef COMPUTE
}

extern "C" void kernel_launch(void* const* d_in, const int* in_sizes, int n_in,
                              void* d_out, int out_size, void* d_ws, size_t ws_size,
                              hipStream_t stream) {
  const int* ids = (const int*)d_in[0];    // [4,4096] int32
  const float* W = (const float*)d_in[1];  // [50257,1024] f32
  const float* R = (const float*)d_in[2];  // [1024,1024] f32
  float* out = (float*)d_out;              // [4,4096,1024] f32
  short* RT = (short*)d_ws;                // 2 MB bf16 R^T

  convert_R_kernel<<<dim3(32, 32), dim3(32, 8), 0, stream>>>(R, RT);
  rot_embed_gemm<<<dim3(256), dim3(512), 99328, stream>>>(W, RT, ids, out);
}

// Round 6
// 63.947 us; speedup vs baseline: 1.1012x; 1.1012x over previous
//
#include <hip/hip_runtime.h>
#include <hip/hip_bf16.h>

// RotatedEmbedding: out[m,:] = W[ids[m],:] @ R  (M=16384, K=N=1024)
// prep: R -> RT bf16 (transposed). Main: FUSED gather-GEMM, 256x256 tile,
// BK=32, 8 waves, 3 LDS buffers, 2-tile lookahead. A = gathered W rows (f32)
// reg-staged (T14), converted+ds_written (swizzled) 1 tile ahead. B = RT via
// global_load_lds w/ pre-swizzled source (rule #21). Counted vmcnt (T4),
// setprio (T5), XCD-bijective swizzle (T1). NO sched_barrier pinning (m141).
// LDS chunk swizzle: slot = chunk ^ ((row ^ (row>>2)) & 3)  (2-way max).

typedef __attribute__((ext_vector_type(4))) float f32x4;
typedef __attribute__((ext_vector_type(8))) short s16x8;

#define DIM 1024
#define NT 32  // K-tiles (BK=32)

__device__ __forceinline__ short f2bf(float f) {
  unsigned u = __float_as_uint(f);
  unsigned r = (u + 0x7FFFu + ((u >> 16) & 1u)) >> 16;  // RNE
  return (short)r;
}

__device__ __forceinline__ void gload_lds16(const void* g, void* l) {
  __builtin_amdgcn_global_load_lds((const __attribute__((address_space(1))) void*)g,
                                   (__attribute__((address_space(3))) void*)l, 16, 0, 0);
}

// R [K][N] f32 -> RT [N][K] bf16
__global__ __launch_bounds__(256) void convert_R_kernel(const float* __restrict__ R,
                                                        short* __restrict__ RT) {
  __shared__ float tile[32][33];
  const int bx = blockIdx.x, by = blockIdx.y;
  const int tx = threadIdx.x, ty = threadIdx.y;
#pragma unroll
  for (int i = 0; i < 4; ++i)
    tile[ty + i * 8][tx] = R[(size_t)(by * 32 + ty + i * 8) * DIM + bx * 32 + tx];
  __syncthreads();
#pragma unroll
  for (int i = 0; i < 4; ++i)
    RT[(size_t)(bx * 32 + ty + i * 8) * DIM + by * 32 + tx] = f2bf(tile[tx][ty + i * 8]);
}

// Fused gather-GEMM. Grid 256 x 512 threads. Dynamic LDS 99328 B:
// [0,48K) A bufs x3, [48K,96K) B bufs x3 (16 KB each, 64 B rows), [96K,+1K) ids.
__global__ __launch_bounds__(512, 2) void rot_embed_gemm(const float* __restrict__ W,
                                                         const short* __restrict__ RT,
                                                         const int* __restrict__ ids,
                                                         float* __restrict__ out) {
  extern __shared__ char smem[];

  const int t = threadIdx.x;
  const int b = blockIdx.x;
  // T1: XCD-bijective (256 blocks): XCD x -> m-panels [x*8,(x+1)*8), all n.
  // The 4 n-sibling blocks of a panel share an XCD -> gather reads dedup in L2.
  const int swz = (b & 7) * 32 + (b >> 3);
  const int m0 = (swz >> 2) * 256;
  const int n0 = (swz & 3) * 256;

  int* sIds = (int*)(smem + 98304);
  if (t < 256) sIds[t] = ids[m0 + t];
  __syncthreads();

  const int lane = t & 63;
  const int w = t >> 6;
  const int wm = w >> 2, wn = w & 3;
  const int fr = lane & 15, fq = lane >> 4;

  char* const ldsA = smem;
  char* const ldsB = smem + 49152;

  // B staging: 2 gload_lds/thread, linear LDS dest, pre-swizzled global source.
  // LDS row srow = w*16 + (lane>>2); slot = lane&3 must hold logical chunk
  // c = (lane&3) ^ ((srow ^ (srow>>2))&3) = (lane&3)^((lane>>2)&3)^((lane>>4)&3).
  const int srow = w * 16 + (lane >> 2);
  const int schunk = ((lane & 3) ^ ((lane >> 2) & 3) ^ ((lane >> 4) & 3)) * 8;
  const short* gB0 = RT + (size_t)(n0 + srow) * DIM + schunk;
  const short* gB1 = RT + (size_t)(n0 + 128 + srow) * DIM + schunk;

  // A gather (reg-staged): thread t -> row rA=t>>1, f32 cols [h*16,(h+1)*16)
  const int rA = t >> 1;
  const int h = t & 1;
  const float* gA = W + (size_t)sIds[rA] * DIM + h * 16;
  const int axor = (rA ^ (rA >> 2)) & 3;
  const int wo0 = rA * 64 + (((h * 2) ^ axor) << 4);      // logical chunk 2h
  const int wo1 = rA * 64 + (((h * 2 + 1) ^ axor) << 4);  // chunk 2h+1

#define ALD(av, kt)                                  \
  {                                                  \
    const f32x4* p = (const f32x4*)(gA + (kt) * 32); \
    av[0] = p[0]; av[1] = p[1]; av[2] = p[2]; av[3] = p[3]; \
  }
#define BST(off, kt)                                                  \
  {                                                                   \
    gload_lds16(gB0 + (kt) * 32, ldsB + (off) + w * 1024);            \
    gload_lds16(gB1 + (kt) * 32, ldsB + (off) + w * 1024 + 8192);     \
  }
#define AWR(av, off)                                                  \
  {                                                                   \
    s16x8 p0, p1;                                                     \
    _Pragma("unroll") for (int e = 0; e < 4; ++e) {                   \
      p0[e] = f2bf(av[0][e]); p0[4 + e] = f2bf(av[1][e]);             \
      p1[e] = f2bf(av[2][e]); p1[4 + e] = f2bf(av[3][e]);             \
    }                                                                 \
    *(s16x8*)(ldsA + (off) + wo0) = p0;                               \
    *(s16x8*)(ldsA + (off) + wo1) = p1;                               \
  }
#define COMPUTE(off)                                                         \
  {                                                                          \
    const char* Abuf = ldsA + (off);                                         \
    const char* Bbuf = ldsB + (off);                                         \
    s16x8 af[8], bfv[4];                                                     \
    _Pragma("unroll") for (int mi = 0; mi < 8; ++mi)                         \
        af[mi] = *(const s16x8*)(Abuf + (wm * 128 + mi * 16 + fr) * 64 + sc);\
    _Pragma("unroll") for (int nj = 0; nj < 4; ++nj)                         \
        bfv[nj] = *(const s16x8*)(Bbuf + (wn * 64 + nj * 16 + fr) * 64 + sc);\
    __builtin_amdgcn_s_setprio(1);                                           \
    _Pragma("unroll") for (int mi = 0; mi < 8; ++mi)                         \
        _Pragma("unroll") for (int nj = 0; nj < 4; ++nj)                     \
            acc[mi][nj] = __builtin_amdgcn_mfma_f32_16x16x32_bf16(           \
                af[mi], bfv[nj], acc[mi][nj], 0, 0, 0);                      \
    __builtin_amdgcn_s_setprio(0);                                           \
  }

  // read slot (loop-invariant): chunk fq of row r; ((r^(r>>2))&3) = (fr&3)^((fr>>2)&3)
  const int sc = ((fq ^ (fr & 3) ^ ((fr >> 2) & 3)) << 4);

  f32x4 acc[8][4];
#pragma unroll
  for (int i = 0; i < 8; ++i)
#pragma unroll
    for (int j = 0; j < 4; ++j) acc[i][j] = (f32x4)0.0f;

  f32x4 avE[4], avO[4];  // A-reg sets, static indexing (rule #20)

  // ---- prologue ----
  ALD(avE, 0);             // A0 x4
  BST(0, 0);               // B0 x2
  ALD(avO, 1);             // A1 x4
  BST(16384, 1);           // B1 x2
  asm volatile("s_waitcnt vmcnt(8)" ::: "memory");  // A0 landed
  AWR(avE, 0);
  asm volatile("s_waitcnt vmcnt(6)" ::: "memory");  // B0 landed
  asm volatile("s_waitcnt lgkmcnt(0)" ::: "memory");
  __builtin_amdgcn_s_barrier();

  int offR = 0, offW = 16384, offS = 32768;

  for (int kt = 0; kt < NT; kt += 2) {
    // ---- even body: compute tile kt ----
    if (kt + 2 < NT) {
      BST(offS, kt + 2);
      ALD(avE, kt + 2);
      asm volatile("s_waitcnt vmcnt(6)" ::: "memory");  // A(kt+1),B(kt+1) landed
    } else {
      asm volatile("s_waitcnt vmcnt(0)" ::: "memory");
    }
    AWR(avO, offW);  // tile kt+1 -> buf W
    COMPUTE(offR);
    asm volatile("s_waitcnt lgkmcnt(0)" ::: "memory");
    __builtin_amdgcn_s_barrier();
    { const int tmp = offR; offR = offW; offW = offS; offS = tmp; }

    // ---- odd body: compute tile kt+1 ----
    if (kt + 3 < NT) {
      BST(offS, kt + 3);
      ALD(avO, kt + 3);
      asm volatile("s_waitcnt vmcnt(6)" ::: "memory");
    } else {
      asm volatile("s_waitcnt vmcnt(0)" ::: "memory");
    }
    if (kt + 2 < NT) AWR(avE, offW);  // tile kt+2 -> buf W
    COMPUTE(offR);
    asm volatile("s_waitcnt lgkmcnt(0)" ::: "memory");
    __builtin_amdgcn_s_barrier();
    { const int tmp = offR; offR = offW; offW = offS; offS = tmp; }
  }

  // ---- epilogue: D col=lane&15, row=(lane>>4)*4+reg (m89-verified) ----
#pragma unroll
  for (int mi = 0; mi < 8; ++mi)
#pragma unroll
    for (int nj = 0; nj < 4; ++nj) {
      float* op = out + (size_t)(m0 + wm * 128 + mi * 16 + fq * 4) * DIM +
                  (n0 + wn * 64 + nj * 16 + fr);
#pragma unroll
      for (int r = 0; r < 4; ++r) op[(size_t)r * DIM] = acc[mi][nj][r];
    }
#undef ALD
#undef BST
#undef AWR
#undef COMPUTE
}

extern "C" void kernel_launch(void* const* d_in, const int* in_sizes, int n_in,
                              void* d_out, int out_size, void* d_ws, size_t ws_size,
                              hipStream_t stream) {
  const int* ids = (const int*)d_in[0];    // [4,4096] int32
  const float* W = (const float*)d_in[1];  // [50257,1024] f32
  const float* R = (const float*)d_in[2];  // [1024,1024] f32
  float* out = (float*)d_out;              // [4,4096,1024] f32
  short* RT = (short*)d_ws;                // 2 MB bf16 R^T

  convert_R_kernel<<<dim3(32, 32), dim3(32, 8), 0, stream>>>(R, RT);
  rot_embed_gemm<<<dim3(256), dim3(512), 99328, stream>>>(W, RT, ids, out);
}

// Round 7
// 57.424 us; speedup vs baseline: 1.2263x; 1.1136x over previous
//
#include <hip/hip_runtime.h>
#include <hip/hip_bf16.h>

// RotatedEmbedding: out[m,:] = W[ids[m],:] @ R  (M=16384, K=N=1024)
// Stage 1 (prep, one launch): R->RT bf16 transposed || gather W rows -> G bf16.
// Stage 2 GEMM: 256x256 tile, BK=64, NT=16, 8 waves. A(G) 3-buf / B(RT) 2-buf
// = 160 KB LDS, all staging via global_load_lds w/ pre-swizzled source
// (slot = chunk ^ (row&7), 2-way residual = free). Exact vmcnt ledger:
// issue B(t+1) then A(t+2); steady wait vmcnt(4) -> A lookahead ~1230cy.

typedef __attribute__((ext_vector_type(4))) float f32x4;
typedef __attribute__((ext_vector_type(8))) short s16x8;
typedef __attribute__((ext_vector_type(2))) int i32x2;

#define DIM 1024
#define NT 16  // K-tiles (BK=64)

__device__ __forceinline__ short f2bf(float f) {
  unsigned u = __float_as_uint(f);
  unsigned r = (u + 0x7FFFu + ((u >> 16) & 1u)) >> 16;  // RNE
  return (short)r;
}

__device__ __forceinline__ void gload_lds16(const void* g, void* l) {
  __builtin_amdgcn_global_load_lds((const __attribute__((address_space(1))) void*)g,
                                   (__attribute__((address_space(3))) void*)l, 16, 0, 0);
}

// blocks [0,1024): R [K][N] f32 -> RT [N][K] bf16; [1024,3072): gather G rows.
__global__ __launch_bounds__(256) void prep_kernel(const float* __restrict__ R,
                                                   short* __restrict__ RT,
                                                   const float* __restrict__ W,
                                                   const int* __restrict__ ids,
                                                   short* __restrict__ G) {
  const int b = blockIdx.x;
  const int t = threadIdx.x;
  if (b < 1024) {
    __shared__ float tile[32][33];
    const int bx = b & 31, by = b >> 5;
    const int tx = t & 31, ty = t >> 5;
#pragma unroll
    for (int i = 0; i < 4; ++i)
      tile[ty + i * 8][tx] = R[(size_t)(by * 32 + ty + i * 8) * DIM + bx * 32 + tx];
    __syncthreads();
#pragma unroll
    for (int i = 0; i < 4; ++i)
      RT[(size_t)(bx * 32 + ty + i * 8) * DIM + by * 32 + tx] = f2bf(tile[tx][ty + i * 8]);
  } else {  // G[m][k] = bf16(W[ids[m]][k]), coalesced f32x4 -> 4xbf16
    const int tid = (b - 1024) * 256 + t;
#pragma unroll
    for (int i = 0; i < 8; ++i) {
      const int g = tid + i * (2048 * 256);
      const int row = g >> 8;
      const int c4 = (g & 255) << 2;
      const f32x4 v = *(const f32x4*)(W + (size_t)ids[row] * DIM + c4);
      i32x2 p;
      p[0] = (int)(unsigned short)f2bf(v[0]) | ((int)f2bf(v[1]) << 16);
      p[1] = (int)(unsigned short)f2bf(v[2]) | ((int)f2bf(v[3]) << 16);
      *(i32x2*)(G + (size_t)g * 4) = p;
    }
  }
}

// GEMM: out[M,N] = G[M,K] * RT[N,K]^T. Grid 256 x 512 threads.
// Dynamic LDS 160 KB: A bufs x3 @ 0/32K/64K, B bufs x2 @ 96K/128K.
// Tile layout: 256 rows x 64 bf16 (128 B rows); 16B slot s holds logical
// chunk s ^ (row&7)  [pre-swizzled source, rule #21].
__global__ __launch_bounds__(512, 2) void rot_embed_gemm(const short* __restrict__ G,
                                                         const short* __restrict__ RT,
                                                         float* __restrict__ out) {
  extern __shared__ char smem[];

  const int t = threadIdx.x;
  const int b = blockIdx.x;
  // T1: XCD-bijective (256 blocks): XCD x -> m-panels [x*8,(x+1)*8), all 4 n
  const int swz = (b & 7) * 32 + (b >> 3);
  const int m0 = (swz >> 2) * 256;
  const int n0 = (swz & 3) * 256;

  const int lane = t & 63;
  const int w = t >> 6;
  const int wm = w >> 2, wn = w & 3;
  const int fr = lane & 15, fq = lane >> 4;

  char* const ldsA = smem;
  char* const ldsB = smem + 98304;

  // Staging: instr j covers LDS rows j*64 + w*8 + (lane>>3), slot lane&7.
  // HW dest = uniform base + lane*16; source chunk = (lane&7) ^ (lane>>3).
  const int srow = w * 8 + (lane >> 3);
  const int sch = ((lane & 7) ^ (lane >> 3)) * 8;  // source col elems
  const short* gA = G + (size_t)(m0 + srow) * DIM + sch;
  const short* gB = RT + (size_t)(n0 + srow) * DIM + sch;
  const int ldsOff = w * 1024;  // wave-uniform base within buffer

#define STA(buf, kt)                                                        \
  {                                                                         \
    _Pragma("unroll") for (int j = 0; j < 4; ++j)                           \
        gload_lds16(gA + (size_t)j * 64 * DIM + (kt) * 64,                  \
                    ldsA + (buf) * 32768 + j * 8192 + ldsOff);              \
  }
#define STB(buf, kt)                                                        \
  {                                                                         \
    _Pragma("unroll") for (int j = 0; j < 4; ++j)                           \
        gload_lds16(gB + (size_t)j * 64 * DIM + (kt) * 64,                  \
                    ldsB + (buf) * 32768 + j * 8192 + ldsOff);              \
  }

  f32x4 acc[8][4];
#pragma unroll
  for (int i = 0; i < 8; ++i)
#pragma unroll
    for (int j = 0; j < 4; ++j) acc[i][j] = (f32x4)0.0f;

  // ---- prologue: A0, B0, A1 (A1 last so steady vmcnt(4) leaves only it) ----
  STA(0, 0);
  STB(0, 0);
  STA(1, 1);

  int bA = 0, bB = 0;
  for (int kt = 0; kt < NT; ++kt) {
    if (kt == NT - 1)
      asm volatile("s_waitcnt vmcnt(0)" ::: "memory");
    else
      asm volatile("s_waitcnt vmcnt(4)" ::: "memory");  // tile kt (A+B) landed
    asm volatile("s_waitcnt lgkmcnt(0)" ::: "memory");  // prev ds_reads drained
    __builtin_amdgcn_s_barrier();

    // issue order: B(kt+1) first, A(kt+2) last (keeps ledger exact)
    if (kt + 1 < NT) STB(bB ^ 1, kt + 1);
    if (kt + 2 < NT) { const int nb = (bA + 2 >= 3) ? bA - 1 : bA + 2; STA(nb, kt + 2); }

    const char* A = ldsA + bA * 32768;
    const char* B = ldsB + bB * 32768;
#pragma unroll
    for (int kk = 0; kk < 2; ++kk) {
      const int sl = ((fq + 4 * kk) ^ (fr & 7)) << 4;  // swizzled 16B slot
      s16x8 af[8], bfv[4];
#pragma unroll
      for (int mi = 0; mi < 8; ++mi)
        af[mi] = *(const s16x8*)(A + (wm * 128 + mi * 16 + fr) * 128 + sl);
#pragma unroll
      for (int nj = 0; nj < 4; ++nj)
        bfv[nj] = *(const s16x8*)(B + (wn * 64 + nj * 16 + fr) * 128 + sl);
      __builtin_amdgcn_s_setprio(1);
#pragma unroll
      for (int mi = 0; mi < 8; ++mi)
#pragma unroll
        for (int nj = 0; nj < 4; ++nj)
          acc[mi][nj] = __builtin_amdgcn_mfma_f32_16x16x32_bf16(af[mi], bfv[nj], acc[mi][nj], 0, 0, 0);
      __builtin_amdgcn_s_setprio(0);
    }

    bA = (bA + 1 == 3) ? 0 : bA + 1;
    bB ^= 1;
  }

  // ---- epilogue: D col=lane&15, row=(lane>>4)*4+reg (m89-verified) ----
#pragma unroll
  for (int mi = 0; mi < 8; ++mi)
#pragma unroll
    for (int nj = 0; nj < 4; ++nj) {
      float* op = out + (size_t)(m0 + wm * 128 + mi * 16 + fq * 4) * DIM +
                  (n0 + wn * 64 + nj * 16 + fr);
#pragma unroll
      for (int r = 0; r < 4; ++r) op[(size_t)r * DIM] = acc[mi][nj][r];
    }
#undef STA
#undef STB
}

extern "C" void kernel_launch(void* const* d_in, const int* in_sizes, int n_in,
                              void* d_out, int out_size, void* d_ws, size_t ws_size,
                              hipStream_t stream) {
  const int* ids = (const int*)d_in[0];    // [4,4096] int32
  const float* W = (const float*)d_in[1];  // [50257,1024] f32
  const float* R = (const float*)d_in[2];  // [1024,1024] f32
  float* out = (float*)d_out;              // [4,4096,1024] f32
  short* RT = (short*)d_ws;                // 2 MB bf16 R^T
  short* G = (short*)d_ws + (size_t)DIM * DIM;  // 32 MB bf16 gathered rows

  prep_kernel<<<dim3(3072), dim3(256), 0, stream>>>(R, RT, W, ids, G);
  rot_embed_gemm<<<dim3(256), dim3(512), 163840, stream>>>(G, RT, out);
}